// Round 6
// baseline (2008.365 us; speedup 1.0000x reference)
//
#include <hip/hip_runtime.h>
#include <hip/hip_bf16.h>

#define B_ 128
#define T_ 256
#define V_ 256
#define U_ 2048

typedef __bf16 bf16x8 __attribute__((ext_vector_type(8)));
typedef float f32x4 __attribute__((ext_vector_type(4)));

union B8u { uint4 u; bf16x8 v; };

static __device__ inline bf16x8 u2b(uint4 u) { B8u t; t.u = u; return t.v; }
static __device__ inline bf16x8 ldg8(const unsigned short* p) {
    B8u t; t.u = *reinterpret_cast<const uint4*>(p); return t.v;
}
static __device__ inline bf16x8 lds8(const char* smem, unsigned off) {
    B8u t; t.u = *reinterpret_cast<const uint4*>(smem + off); return t.v;
}
static __device__ inline unsigned short f2b(float f) {
    __hip_bfloat16 h = __float2bfloat16(f);
    unsigned short r; __builtin_memcpy(&r, &h, 2); return r;
}
// plain CACHED 16B load as volatile asm: compiler cannot sink it into the
// consumer loop (R3/R4 lesson: sunk loads = serialized latency chain)
static __device__ inline uint4 ldg16_c(const unsigned short* p) {
    uint4 r;
    asm volatile("global_load_dwordx4 %0, %1, off"
                 : "=&v"(r) : "v"(p) : "memory");
    return r;
}
// 8B write-through to L3 coherence point (cross-XCD visible after vmcnt drain)
static __device__ inline void stg8_sc(unsigned short* p, uint2 v) {
    asm volatile("global_store_dwordx2 %0, %1, off sc0 sc1"
                 :: "v"(p), "v"(v) : "memory");
}

// ---------------- prep kernels ----------------

// out[c][r] = bf16(in[r][c]);  in: [R][C] f32, out: [C][R] bf16
__global__ void transpose_bf16(const float* __restrict__ in,
                               unsigned short* __restrict__ outp, int R, int C) {
    __shared__ float tile[32][33];
    int tc = blockIdx.x * 32, tr = blockIdx.y * 32;
    int lx = threadIdx.x & 31, ly = threadIdx.x >> 5;  // 256 thr: ly 0..7
#pragma unroll
    for (int i = 0; i < 32; i += 8)
        tile[ly + i][lx] = in[(size_t)(tr + ly + i) * C + tc + lx];
    __syncthreads();
#pragma unroll
    for (int i = 0; i < 32; i += 8)
        outp[(size_t)(tc + ly + i) * R + tr + lx] = f2b(tile[lx][ly + i]);
}

__global__ void conv_h0(const float* __restrict__ h0, unsigned short* __restrict__ hb) {
    int i = blockIdx.x * blockDim.x + threadIdx.x;  // grid covers exactly B_*U_
    hb[i] = f2b(h0[i]);
}

// xT[t][b] = x[b][t]
__global__ void transpose_x(const int* __restrict__ x, int* __restrict__ xT) {
    int i = blockIdx.x * 256 + threadIdx.x;  // grid: 128 blocks
    int b = i >> 8, t = i & 255;
    xT[t * B_ + b] = x[i];
}

// =====================================================================
// Recurrence kernel.
// grid: 256 blocks (4 groups x 64), 256 threads (4 waves), 1 block/CU.
// Block (g,p): batches b0=g*32..+32, u-cols c0=p*32..+32.
// Wave w: K-quarter [w*512, w*512+512) -> LDS f32 reduce across waves.
// Barrier: per-group sub-counters j=p>>3 (cols [256j,256j+256)); consumer
// wave w polls ONLY sub-counters {2w, 2w+1} (its 16 producers) and starts
// loading immediately -- no block-wide join, no global straggler max.
// A loads: plain cached, forced batch-issue via asm, split vmcnt(16)/(0).
// h stores: one dwordx2 sc0sc1 per thread to fresh hs[t+1] (archive).
// =====================================================================
__global__ __launch_bounds__(256, 1) void rnn_arc3(
        const int* __restrict__ xT, const float* __restrict__ Wx,
        const float* __restrict__ bias, const unsigned short* __restrict__ WhT,
        unsigned short* __restrict__ hs, unsigned* __restrict__ ctrs) {
    extern __shared__ char smem[];
    float* red = (float*)(smem + 32 * 2048 * 2);  // [4][32*36] f32

    const int bid = blockIdx.x;
    const int g = bid >> 6, p = bid & 63;
    const int b0 = g * 32, c0 = p * 32;
    const int tid = threadIdx.x;
    const int w = tid >> 6, lane = tid & 63;
    const int lr = lane & 15, lh = lane >> 4;

    // Fill Wh LDS slice: lds[(c*4096 + k8*16) ^ ((c&7)<<4)] = WhT[c0+c][k8*8..+8]
    for (int i = tid; i < 32 * 256; i += 256) {
        int c = i >> 8, k8 = i & 255;
        uint4 v = *reinterpret_cast<const uint4*>(WhT + (size_t)(c0 + c) * U_ + k8 * 8);
        unsigned off = (unsigned)(c * 4096 + k8 * 16) ^ ((unsigned)(c & 7) << 4);
        *reinterpret_cast<uint4*>(smem + off) = v;
    }
    __syncthreads();

    // MFMA-loop constants (wave-local K-quarter)
    const int kbase = w * 512;
    const unsigned lin0 = (unsigned)(lr * 4096) + (unsigned)((kbase + lh * 8) * 2);
    const unsigned lin1 = lin0 + 16 * 4096;
    const unsigned swz = (unsigned)(lr & 7) << 4;

    // epilogue constants: thread -> (row = tid>>3, 4 contiguous cols)
    const int erow = tid >> 3;              // 0..31 local batch row
    const int ec4 = (tid & 7) * 4;          // 0..28 local col (x4)
    const int ucol = c0 + ec4;              // global u column of 4-pack
    const f32x4 bias4 = *reinterpret_cast<const f32x4*>(bias + ucol);

    // prefetch x-projection for step 0 (float4 row-slice of Wx)
    f32x4 xp;
    {
        int tok = xT[0 * B_ + b0 + erow];
        xp = *reinterpret_cast<const f32x4*>(Wx + (size_t)tok * U_ + ucol) + bias4;
    }

    for (int t = 0; t < T_; ++t) {
        const unsigned short* hp = hs + (size_t)t * (B_ * U_);
        unsigned short* hc = hs + (size_t)(t + 1) * (B_ * U_);

        // ---- dependency wait: my K-quarter's 16 producers (2 sub-ctrs) ----
        if (t > 0 && lane < 2) {
            unsigned tgt = (unsigned)t * 8u;
            unsigned* cp = ctrs + (g * 8 + (w * 2 + lane)) * 32;
            while (__hip_atomic_load(cp, __ATOMIC_RELAXED, __HIP_MEMORY_SCOPE_AGENT) < tgt) {}
        }

        // ---- stage 32 A-fragments: forced parallel issue, split wait ----
        const unsigned short* pa0 = hp + (size_t)(b0 + lr) * U_ + kbase + lh * 8;
        const unsigned short* pa1 = pa0 + 16 * U_;
        uint4 areg0[16], areg1[16];
#pragma unroll
        for (int ks = 0; ks < 16; ++ks) {
            areg0[ks] = ldg16_c(pa0 + ks * 32);
            areg1[ks] = ldg16_c(pa1 + ks * 32);
        }

        f32x4 acc00 = {0.f, 0.f, 0.f, 0.f}, acc01 = {0.f, 0.f, 0.f, 0.f};
        f32x4 acc10 = {0.f, 0.f, 0.f, 0.f}, acc11 = {0.f, 0.f, 0.f, 0.f};

        // first half: oldest 16 loads (ks 0..7) done once <=16 outstanding
        asm volatile("s_waitcnt vmcnt(16)" ::: "memory");
        __builtin_amdgcn_sched_barrier(0);
#pragma unroll
        for (int ks = 0; ks < 8; ++ks) {
            bf16x8 a0 = u2b(areg0[ks]);
            bf16x8 a1 = u2b(areg1[ks]);
            bf16x8 bb0 = lds8(smem, (lin0 + (unsigned)ks * 64u) ^ swz);
            bf16x8 bb1 = lds8(smem, (lin1 + (unsigned)ks * 64u) ^ swz);
            acc00 = __builtin_amdgcn_mfma_f32_16x16x32_bf16(a0, bb0, acc00, 0, 0, 0);
            acc01 = __builtin_amdgcn_mfma_f32_16x16x32_bf16(a0, bb1, acc01, 0, 0, 0);
            acc10 = __builtin_amdgcn_mfma_f32_16x16x32_bf16(a1, bb0, acc10, 0, 0, 0);
            acc11 = __builtin_amdgcn_mfma_f32_16x16x32_bf16(a1, bb1, acc11, 0, 0, 0);
        }
        asm volatile("s_waitcnt vmcnt(0)" ::: "memory");
        __builtin_amdgcn_sched_barrier(0);
#pragma unroll
        for (int ks = 8; ks < 16; ++ks) {
            bf16x8 a0 = u2b(areg0[ks]);
            bf16x8 a1 = u2b(areg1[ks]);
            bf16x8 bb0 = lds8(smem, (lin0 + (unsigned)ks * 64u) ^ swz);
            bf16x8 bb1 = lds8(smem, (lin1 + (unsigned)ks * 64u) ^ swz);
            acc00 = __builtin_amdgcn_mfma_f32_16x16x32_bf16(a0, bb0, acc00, 0, 0, 0);
            acc01 = __builtin_amdgcn_mfma_f32_16x16x32_bf16(a0, bb1, acc01, 0, 0, 0);
            acc10 = __builtin_amdgcn_mfma_f32_16x16x32_bf16(a1, bb0, acc10, 0, 0, 0);
            acc11 = __builtin_amdgcn_mfma_f32_16x16x32_bf16(a1, bb1, acc11, 0, 0, 0);
        }

        // ---- split-K partials -> LDS (C-layout: row=lh*4+r, col=lr) ----
        float* redw = red + w * 1152;
#pragma unroll
        for (int r = 0; r < 4; ++r) {
            redw[(lh * 4 + r) * 36 + lr] = acc00[r];
            redw[(lh * 4 + r) * 36 + 16 + lr] = acc01[r];
            redw[(16 + lh * 4 + r) * 36 + lr] = acc10[r];
            redw[(16 + lh * 4 + r) * 36 + 16 + lr] = acc11[r];
        }
        __syncthreads();  // join A: all partials visible

        // ---- reduce (float4) + tanh + one dwordx2 sc store per thread ----
        {
            const int o = erow * 36 + ec4;
            f32x4 z = *reinterpret_cast<f32x4*>(red + 0 * 1152 + o);
            z += *reinterpret_cast<f32x4*>(red + 1 * 1152 + o);
            z += *reinterpret_cast<f32x4*>(red + 2 * 1152 + o);
            z += *reinterpret_cast<f32x4*>(red + 3 * 1152 + o);
            z += xp;
            unsigned lo = (unsigned)f2b(tanhf(z[0])) | ((unsigned)f2b(tanhf(z[1])) << 16);
            unsigned hi = (unsigned)f2b(tanhf(z[2])) | ((unsigned)f2b(tanhf(z[3])) << 16);
            stg8_sc(hc + (size_t)(b0 + erow) * U_ + ucol, make_uint2(lo, hi));
        }

        // prefetch next step's x-projection (hides under store drain)
        if (t + 1 < T_) {
            int tok = xT[(t + 1) * B_ + b0 + erow];
            xp = *reinterpret_cast<const f32x4*>(Wx + (size_t)tok * U_ + ucol) + bias4;
        }

        // ---- drain sc stores to coherence point; join B doubles as
        //      red-read-complete barrier (safe to overwrite next step) ----
        asm volatile("s_waitcnt vmcnt(0)" ::: "memory");
        __syncthreads();
        if (tid == 0)
            __hip_atomic_fetch_add(ctrs + (g * 8 + (p >> 3)) * 32, 1u,
                                   __ATOMIC_RELAXED, __HIP_MEMORY_SCOPE_AGENT);
    }
}

// =====================================================================
// Decode GEMM: logits[b,t,v] = hs[t+1][b] . WdT[v] + bd[v]
// hsD = hs + B*U viewed as [T*B][U]; out row = (b*T + t).
// 256 blocks x 4 waves; each wave: 32 rows x 256 cols, full K.
// =====================================================================
__global__ __launch_bounds__(256, 1) void decode_gemm(
        const unsigned short* __restrict__ hsD, const unsigned short* __restrict__ WdT,
        const float* __restrict__ bdv, float* __restrict__ out) {
    const int tid = threadIdx.x;
    const int w = tid >> 6, lane = tid & 63;
    const int lr = lane & 15, lh = lane >> 4;
    const int r0 = blockIdx.x * 128 + w * 32;

    const unsigned short* pa0 = hsD + (size_t)(r0 + lr) * U_ + lh * 8;
    const unsigned short* pa1 = pa0 + (size_t)16 * U_;
    const unsigned short* pb = WdT + (size_t)lr * U_ + lh * 8;

    f32x4 acc0[16], acc1[16];
#pragma unroll
    for (int n = 0; n < 16; ++n) {
        acc0[n] = (f32x4){0.f, 0.f, 0.f, 0.f};
        acc1[n] = (f32x4){0.f, 0.f, 0.f, 0.f};
    }

    for (int ks = 0; ks < 64; ++ks) {
        bf16x8 a0 = ldg8(pa0 + ks * 32);
        bf16x8 a1 = ldg8(pa1 + ks * 32);
#pragma unroll
        for (int n = 0; n < 16; ++n) {
            bf16x8 bb = ldg8(pb + (size_t)n * 16 * U_ + ks * 32);
            acc0[n] = __builtin_amdgcn_mfma_f32_16x16x32_bf16(a0, bb, acc0[n], 0, 0, 0);
            acc1[n] = __builtin_amdgcn_mfma_f32_16x16x32_bf16(a1, bb, acc1[n], 0, 0, 0);
        }
    }

#pragma unroll
    for (int n = 0; n < 16; ++n) {
        float bd_ = bdv[n * 16 + lr];
#pragma unroll
        for (int r = 0; r < 4; ++r) {
            int m0 = r0 + lh * 4 + r;        // hsD row = t*B + b
            int m1 = m0 + 16;
            out[((size_t)(m0 & 127) * T_ + (m0 >> 7)) * V_ + n * 16 + lr] = acc0[n][r] + bd_;
            out[((size_t)(m1 & 127) * T_ + (m1 >> 7)) * V_ + n * 16 + lr] = acc1[n][r] + bd_;
        }
    }
}

// ---------------- launch ----------------
extern "C" void kernel_launch(void* const* d_in, const int* in_sizes, int n_in,
                              void* d_out, int out_size, void* d_ws, size_t ws_size,
                              hipStream_t stream) {
    const int* x = (const int*)d_in[0];
    const float* Wx = (const float*)d_in[1];
    const float* Wh = (const float*)d_in[2];
    const float* b = (const float*)d_in[3];
    const float* Wd = (const float*)d_in[4];
    const float* bd = (const float*)d_in[5];
    const float* h0 = (const float*)d_in[6];
    float* out = (float*)d_out;

    char* ws = (char*)d_ws;

    const size_t OFF_WhT = 0;                 // 8,388,608
    const size_t OFF_WdT = 8388608;           // 1,048,576
    const size_t OFF_xT = 9437184;            // 131,072
    const size_t OFF_CTR = 9568256;           // 4,096 (32 ctrs @ 128B spacing)
    const size_t OFF_HS = 9572352;            // 257 * 524,288

    unsigned short* WhT = (unsigned short*)(ws + OFF_WhT);
    unsigned short* WdT = (unsigned short*)(ws + OFF_WdT);
    int* xT = (int*)(ws + OFF_xT);
    unsigned* ctrs = (unsigned*)(ws + OFF_CTR);
    unsigned short* hs = (unsigned short*)(ws + OFF_HS);

    hipMemsetAsync(ctrs, 0, 4096, stream);
    transpose_bf16<<<dim3(64, 64), 256, 0, stream>>>(Wh, WhT, 2048, 2048);
    transpose_bf16<<<dim3(8, 64), 256, 0, stream>>>(Wd, WdT, 2048, 256);
    conv_h0<<<1024, 256, 0, stream>>>(h0, hs);  // h_{-1} -> hs[0]
    transpose_x<<<128, 256, 0, stream>>>(x, xT);

    const int smem_bytes = 32 * 2048 * 2 + 4 * 1152 * 4;  // 149,504 B
    hipFuncSetAttribute((const void*)rnn_arc3, hipFuncAttributeMaxDynamicSharedMemorySize,
                        smem_bytes);
    void* args[] = {(void*)&xT, (void*)&Wx, (void*)&b, (void*)&WhT, (void*)&hs,
                    (void*)&ctrs};
    hipLaunchCooperativeKernel((const void*)rnn_arc3, dim3(256), dim3(256), args,
                               (unsigned)smem_bytes, stream);

    const unsigned short* hsD = hs + (size_t)B_ * U_;
    decode_gemm<<<256, 256, 0, stream>>>(hsD, WdT, bd, out);
}

// Round 10
// 1935.006 us; speedup vs baseline: 1.0379x; 1.0379x over previous
//
#include <hip/hip_runtime.h>
#include <hip/hip_bf16.h>

#define B_ 128
#define T_ 256
#define V_ 256
#define U_ 2048

typedef __bf16 bf16x8 __attribute__((ext_vector_type(8)));
typedef float f32x4 __attribute__((ext_vector_type(4)));

union B8u { uint4 u; bf16x8 v; };

static __device__ inline bf16x8 u2b(uint4 u) { B8u t; t.u = u; return t.v; }
static __device__ inline bf16x8 ldg8(const unsigned short* p) {
    B8u t; t.u = *reinterpret_cast<const uint4*>(p); return t.v;
}
static __device__ inline bf16x8 lds8(const char* smem, unsigned off) {
    B8u t; t.u = *reinterpret_cast<const uint4*>(smem + off); return t.v;
}
static __device__ inline unsigned short f2b(float f) {
    __hip_bfloat16 h = __float2bfloat16(f);
    unsigned short r; __builtin_memcpy(&r, &h, 2); return r;
}
// plain CACHED 16B load as volatile asm: compiler cannot sink it into the
// consumer loop (R3/R4 lesson: sunk loads = serialized latency chain)
static __device__ inline uint4 ldg16_c(const unsigned short* p) {
    uint4 r;
    asm volatile("global_load_dwordx4 %0, %1, off"
                 : "=&v"(r) : "v"(p) : "memory");
    return r;
}
// 8B write-through to L3 coherence point (cross-XCD visible after vmcnt drain)
static __device__ inline void stg8_sc(unsigned short* p, uint2 v) {
    asm volatile("global_store_dwordx2 %0, %1, off sc0 sc1"
                 :: "v"(p), "v"(v) : "memory");
}

// ---------------- prep kernels ----------------

// out[c][r] = bf16(in[r][c]);  in: [R][C] f32, out: [C][R] bf16
__global__ void transpose_bf16(const float* __restrict__ in,
                               unsigned short* __restrict__ outp, int R, int C) {
    __shared__ float tile[32][33];
    int tc = blockIdx.x * 32, tr = blockIdx.y * 32;
    int lx = threadIdx.x & 31, ly = threadIdx.x >> 5;  // 256 thr: ly 0..7
#pragma unroll
    for (int i = 0; i < 32; i += 8)
        tile[ly + i][lx] = in[(size_t)(tr + ly + i) * C + tc + lx];
    __syncthreads();
#pragma unroll
    for (int i = 0; i < 32; i += 8)
        outp[(size_t)(tc + ly + i) * R + tr + lx] = f2b(tile[lx][ly + i]);
}

__global__ void conv_h0(const float* __restrict__ h0, unsigned short* __restrict__ hb) {
    int i = blockIdx.x * blockDim.x + threadIdx.x;  // grid covers exactly B_*U_
    hb[i] = f2b(h0[i]);
}

// xT[t][b] = x[b][t]
__global__ void transpose_x(const int* __restrict__ x, int* __restrict__ xT) {
    int i = blockIdx.x * 256 + threadIdx.x;  // grid: 128 blocks
    int b = i >> 8, t = i & 255;
    xT[t * B_ + b] = x[i];
}

// =====================================================================
// Recurrence kernel -- R5 VERBATIM (proven: 1935us, absmax 0.009277).
// The R7-R9 data-flow-sync (sentinel+retry, no drains) experiment NaN'd
// three structurally-different ways; root cause unresolved at source level
// (suspect: regalloc copies/spills of in-flight asm-load dests that pass
// the sentinel check with stale data). Reverted to the counter barrier.
//
// grid: 256 blocks (4 groups x 64), 256 threads (4 waves), 1 block/CU.
// Block (g,p): batches b0=g*32..+32, u-cols c0=p*32..+32.
// Wave w: K-quarter [w*512, w*512+512) of the 32x32 tile -> LDS f32 reduce.
// A (h_{t-1}) loads: plain cached, FORCED batch-issue via volatile asm
// (32 loads in flight -> single vmcnt wait), L2-shared across same-XCD blocks.
// h_t stores: sc0sc1 write-through to fresh hs[t+1] address (archive ->
// cached reads are never stale: any hit is current or bit-identical replay).
// Barrier: per-group, 8-way split counters (8 blocks per sub-counter).
// =====================================================================
__global__ __launch_bounds__(256, 1) void rnn_arc2(
        const int* __restrict__ xT, const float* __restrict__ Wx,
        const float* __restrict__ bias, const unsigned short* __restrict__ WhT,
        unsigned short* __restrict__ hs, unsigned* __restrict__ ctrs) {
    extern __shared__ char smem[];
    float* red = (float*)(smem + 32 * 2048 * 2);  // [4][32*36] f32

    const int bid = blockIdx.x;
    const int g = bid >> 6, p = bid & 63;
    const int b0 = g * 32, c0 = p * 32;
    const int tid = threadIdx.x;
    const int w = tid >> 6, lane = tid & 63;
    const int lr = lane & 15, lh = lane >> 4;

    // Fill Wh LDS slice: lds[(c*4096 + k8*16) ^ ((c&7)<<4)] = WhT[c0+c][k8*8..+8]
    for (int i = tid; i < 32 * 256; i += 256) {
        int c = i >> 8, k8 = i & 255;
        uint4 v = *reinterpret_cast<const uint4*>(WhT + (size_t)(c0 + c) * U_ + k8 * 8);
        unsigned off = (unsigned)(c * 4096 + k8 * 16) ^ ((unsigned)(c & 7) << 4);
        *reinterpret_cast<uint4*>(smem + off) = v;
    }
    __syncthreads();

    // MFMA-loop constants (wave-local K-quarter)
    const int kbase = w * 512;
    const unsigned lin0 = (unsigned)(lr * 4096) + (unsigned)((kbase + lh * 8) * 2);
    const unsigned lin1 = lin0 + 16 * 4096;
    const unsigned swz = (unsigned)(lr & 7) << 4;

    // epilogue constants: thread -> (row = tid>>3, 4 contiguous cols)
    const int erow = tid >> 3;              // 0..31 local batch row
    const int ec4 = (tid & 7) * 4;          // 0..28 local col (x4)
    const int ucol = c0 + ec4;              // global u column of 4-pack
    const f32x4 bias4 = *reinterpret_cast<const f32x4*>(bias + ucol);

    // prefetch x-projection for step 0 (float4 row-slice of Wx)
    f32x4 xp;
    {
        int tok = xT[0 * B_ + b0 + erow];
        xp = *reinterpret_cast<const f32x4*>(Wx + (size_t)tok * U_ + ucol) + bias4;
    }

    for (int t = 0; t < T_; ++t) {
        const unsigned short* hp = hs + (size_t)t * (B_ * U_);
        unsigned short* hc = hs + (size_t)(t + 1) * (B_ * U_);

        // ---- stage all 32 A-fragments upfront: forced parallel issue ----
        const unsigned short* pa0 = hp + (size_t)(b0 + lr) * U_ + kbase + lh * 8;
        const unsigned short* pa1 = pa0 + 16 * U_;
        uint4 areg0[16], areg1[16];
#pragma unroll
        for (int ks = 0; ks < 16; ++ks) {
            areg0[ks] = ldg16_c(pa0 + ks * 32);
            areg1[ks] = ldg16_c(pa1 + ks * 32);
        }
        asm volatile("s_waitcnt vmcnt(0)" ::: "memory");
        __builtin_amdgcn_sched_barrier(0);

        // ---- load-free MFMA loop over the K-quarter ----
        f32x4 acc00 = {0.f, 0.f, 0.f, 0.f}, acc01 = {0.f, 0.f, 0.f, 0.f};
        f32x4 acc10 = {0.f, 0.f, 0.f, 0.f}, acc11 = {0.f, 0.f, 0.f, 0.f};
#pragma unroll
        for (int ks = 0; ks < 16; ++ks) {
            bf16x8 a0 = u2b(areg0[ks]);
            bf16x8 a1 = u2b(areg1[ks]);
            bf16x8 bb0 = lds8(smem, (lin0 + (unsigned)ks * 64u) ^ swz);
            bf16x8 bb1 = lds8(smem, (lin1 + (unsigned)ks * 64u) ^ swz);
            acc00 = __builtin_amdgcn_mfma_f32_16x16x32_bf16(a0, bb0, acc00, 0, 0, 0);
            acc01 = __builtin_amdgcn_mfma_f32_16x16x32_bf16(a0, bb1, acc01, 0, 0, 0);
            acc10 = __builtin_amdgcn_mfma_f32_16x16x32_bf16(a1, bb0, acc10, 0, 0, 0);
            acc11 = __builtin_amdgcn_mfma_f32_16x16x32_bf16(a1, bb1, acc11, 0, 0, 0);
        }

        // ---- split-K partials -> LDS (2-way bank pattern, free) ----
        float* redw = red + w * 1152;
#pragma unroll
        for (int r = 0; r < 4; ++r) {
            redw[(lh * 4 + r) * 36 + lr] = acc00[r];
            redw[(lh * 4 + r) * 36 + 16 + lr] = acc01[r];
            redw[(16 + lh * 4 + r) * 36 + lr] = acc10[r];
            redw[(16 + lh * 4 + r) * 36 + 16 + lr] = acc11[r];
        }
        __syncthreads();

        // ---- reduce (float4) + tanh + one dwordx2 sc store per thread ----
        {
            const int o = erow * 36 + ec4;
            f32x4 z = *reinterpret_cast<f32x4*>(red + 0 * 1152 + o);
            z += *reinterpret_cast<f32x4*>(red + 1 * 1152 + o);
            z += *reinterpret_cast<f32x4*>(red + 2 * 1152 + o);
            z += *reinterpret_cast<f32x4*>(red + 3 * 1152 + o);
            z += xp;
            unsigned lo = (unsigned)f2b(tanhf(z[0])) | ((unsigned)f2b(tanhf(z[1])) << 16);
            unsigned hi = (unsigned)f2b(tanhf(z[2])) | ((unsigned)f2b(tanhf(z[3])) << 16);
            stg8_sc(hc + (size_t)(b0 + erow) * U_ + ucol, make_uint2(lo, hi));
        }

        // prefetch next step's x-projection (independent; hides under drain)
        if (t + 1 < T_) {
            int tok = xT[(t + 1) * B_ + b0 + erow];
            xp = *reinterpret_cast<const f32x4*>(Wx + (size_t)tok * U_ + ucol) + bias4;
        }

        // ---- drain sc stores to L3, block-join, arrive (8-way split ctr) ----
        asm volatile("s_waitcnt vmcnt(0)" ::: "memory");
        __syncthreads();
        if (tid == 0)
            __hip_atomic_fetch_add(ctrs + (g * 8 + (p & 7)) * 32, 1u,
                                   __ATOMIC_RELAXED, __HIP_MEMORY_SCOPE_AGENT);

        // ---- wait: each of 8 sub-counters must reach 8*(t+1); wave 0 polls,
        //      lane k watches sub-counter k&7 (8 parallel L3 lines) ----
        if (w == 0) {
            unsigned tgt = (unsigned)(t + 1) * 8u;
            unsigned* cp = ctrs + (g * 8 + (lane & 7)) * 32;
            while (__hip_atomic_load(cp, __ATOMIC_RELAXED, __HIP_MEMORY_SCOPE_AGENT) < tgt)
                __builtin_amdgcn_s_sleep(1);
        }
        __syncthreads();
    }
}

// =====================================================================
// Decode GEMM v2: logits[b,t,v] = hs[t+1][b] . WdT[v] + bd[v]
// hsD = hs + B*U viewed as [T*B][U]; out row = (b*T + t).
// Old version: 256 blocks, wave = 32 rows x 256 cols, 18 sunk loads per
// k-step, 4 waves/CU -> latency-serial, ~100us for 34 GFLOP (0.3 TF).
// v2: 1024 blocks x 4 waves; wave = 32 rows x 64 cols (acc = 32 VGPR,
// 6 loads + 8 MFMA per k-step, ~100 VGPR total) -> 2+ blocks/CU, >=16
// waves/CU of TLP hides the load latency; WdT (1MB) L2-resident.
// =====================================================================
__global__ __launch_bounds__(256, 2) void decode_gemm2(
        const unsigned short* __restrict__ hsD, const unsigned short* __restrict__ WdT,
        const float* __restrict__ bdv, float* __restrict__ out) {
    const int tid = threadIdx.x;
    const int w = tid >> 6, lane = tid & 63;
    const int lr = lane & 15, lh = lane >> 4;
    const int r0 = blockIdx.x * 32;   // 32 hsD rows per block
    const int v0 = w * 64;            // 64 vocab cols per wave

    const unsigned short* pa0 = hsD + (size_t)(r0 + lr) * U_ + lh * 8;
    const unsigned short* pa1 = pa0 + (size_t)16 * U_;
    const unsigned short* pb0 = WdT + (size_t)(v0 + lr) * U_ + lh * 8;

    f32x4 acc0[4], acc1[4];
#pragma unroll
    for (int n = 0; n < 4; ++n) {
        acc0[n] = (f32x4){0.f, 0.f, 0.f, 0.f};
        acc1[n] = (f32x4){0.f, 0.f, 0.f, 0.f};
    }

#pragma unroll 4
    for (int ks = 0; ks < 64; ++ks) {
        bf16x8 a0 = ldg8(pa0 + ks * 32);
        bf16x8 a1 = ldg8(pa1 + ks * 32);
#pragma unroll
        for (int n = 0; n < 4; ++n) {
            bf16x8 bb = ldg8(pb0 + (size_t)n * 16 * U_ + ks * 32);
            acc0[n] = __builtin_amdgcn_mfma_f32_16x16x32_bf16(a0, bb, acc0[n], 0, 0, 0);
            acc1[n] = __builtin_amdgcn_mfma_f32_16x16x32_bf16(a1, bb, acc1[n], 0, 0, 0);
        }
    }

#pragma unroll
    for (int n = 0; n < 4; ++n) {
        float bd_ = bdv[v0 + n * 16 + lr];
#pragma unroll
        for (int r = 0; r < 4; ++r) {
            int m0 = r0 + lh * 4 + r;        // hsD row = t*B + b
            int m1 = m0 + 16;
            out[((size_t)(m0 & 127) * T_ + (m0 >> 7)) * V_ + v0 + n * 16 + lr] =
                acc0[n][r] + bd_;
            out[((size_t)(m1 & 127) * T_ + (m1 >> 7)) * V_ + v0 + n * 16 + lr] =
                acc1[n][r] + bd_;
        }
    }
}

// ---------------- launch ----------------
extern "C" void kernel_launch(void* const* d_in, const int* in_sizes, int n_in,
                              void* d_out, int out_size, void* d_ws, size_t ws_size,
                              hipStream_t stream) {
    const int* x = (const int*)d_in[0];
    const float* Wx = (const float*)d_in[1];
    const float* Wh = (const float*)d_in[2];
    const float* b = (const float*)d_in[3];
    const float* Wd = (const float*)d_in[4];
    const float* bd = (const float*)d_in[5];
    const float* h0 = (const float*)d_in[6];
    float* out = (float*)d_out;

    char* ws = (char*)d_ws;

    const size_t OFF_WhT = 0;                 // 8,388,608
    const size_t OFF_WdT = 8388608;           // 1,048,576
    const size_t OFF_xT = 9437184;            // 131,072
    const size_t OFF_CTR = 9568256;           // 4,096 (32 ctrs @ 128B spacing)
    const size_t OFF_HS = 9572352;            // 257 * 524,288

    unsigned short* WhT = (unsigned short*)(ws + OFF_WhT);
    unsigned short* WdT = (unsigned short*)(ws + OFF_WdT);
    int* xT = (int*)(ws + OFF_xT);
    unsigned* ctrs = (unsigned*)(ws + OFF_CTR);
    unsigned short* hs = (unsigned short*)(ws + OFF_HS);

    hipMemsetAsync(ctrs, 0, 4096, stream);
    transpose_bf16<<<dim3(64, 64), 256, 0, stream>>>(Wh, WhT, 2048, 2048);
    transpose_bf16<<<dim3(8, 64), 256, 0, stream>>>(Wd, WdT, 2048, 256);
    conv_h0<<<1024, 256, 0, stream>>>(h0, hs);  // h_{-1} -> hs[0]
    transpose_x<<<128, 256, 0, stream>>>(x, xT);

    const int smem_bytes = 32 * 2048 * 2 + 4 * 1152 * 4;  // 149,504 B
    hipFuncSetAttribute((const void*)rnn_arc2, hipFuncAttributeMaxDynamicSharedMemorySize,
                        smem_bytes);
    void* args[] = {(void*)&xT, (void*)&Wx, (void*)&b, (void*)&WhT, (void*)&hs,
                    (void*)&ctrs};
    hipLaunchCooperativeKernel((const void*)rnn_arc2, dim3(256), dim3(256), args,
                               (unsigned)smem_bytes, stream);

    const unsigned short* hsD = hs + (size_t)B_ * U_;
    decode_gemm2<<<1024, 256, 0, stream>>>(hsD, WdT, bd, out);
}